// Round 5
// baseline (407.588 us; speedup 1.0000x reference)
//
#include <hip/hip_runtime.h>

#define B_SZ 32768
#define I_SZ 256
#define H_SZ 512
#define K_SZ 768   // I + H
#define NG   2048  // 4*H

typedef _Float16 half8 __attribute__((ext_vector_type(8)));
typedef _Float16 half4v __attribute__((ext_vector_type(4)));
typedef float f32x4 __attribute__((ext_vector_type(4)));

__device__ __forceinline__ float sigf(float x) {
  return __builtin_amdgcn_rcpf(1.0f + __builtin_amdgcn_exp2f(-1.44269504089f * x));
}
__device__ __forceinline__ float tanh_fast(float x) {
  return 1.0f - 2.0f * __builtin_amdgcn_rcpf(1.0f + __builtin_amdgcn_exp2f(2.88539008178f * x));
}

// ---------------- fused pre-pass (grid-stride, 2048 blocks x 256) ----------------
// (verified in round 4; unchanged)
__global__ void __launch_bounds__(256) prepass(const float* __restrict__ x,
                                               const float* __restrict__ h,
                                               const float* __restrict__ Wx,
                                               const float* __restrict__ Wh,
                                               const float* __restrict__ bx,
                                               const float* __restrict__ bh,
                                               _Float16* __restrict__ Aw,
                                               _Float16* __restrict__ Wf,
                                               float* __restrict__ bs) {
  const unsigned t = blockIdx.x * 256 + threadIdx.x;
  const unsigned nthr = gridDim.x * 256;

  // ---- A fragment pack: B_SZ*96 octet units, dest-ordered ----
  const unsigned NA = B_SZ * 96u;
  for (unsigned u = t; u < NA; u += nthr) {
    const unsigned l15 = u & 15u;
    const unsigned l4 = (u >> 4) & 3u;
    const unsigned mi = (u >> 6) & 3u;
    const unsigned wr = (u >> 8) & 1u;
    const unsigned ks = (u >> 9) & 1u;
    const unsigned w3 = u >> 10;          // mb*12 + kb, < 3072
    const unsigned mb = w3 / 12u;         // magic-mul
    const unsigned kb = w3 - mb * 12u;
    const unsigned r = mb * 128u + wr * 64u + mi * 16u + l15;
    const unsigned k = kb * 64u + ks * 32u + l4 * 8u;
    float4 v0, v1;
    if (k < 256u) {
      const float* p = x + (size_t)r * I_SZ + k;
      v0 = *(const float4*)p; v1 = *(const float4*)(p + 4);
    } else {
      const float* p = h + (size_t)r * H_SZ + (k - 256u);
      v0 = *(const float4*)p; v1 = *(const float4*)(p + 4);
    }
    half8 o = {(_Float16)v0.x, (_Float16)v0.y, (_Float16)v0.z, (_Float16)v0.w,
               (_Float16)v1.x, (_Float16)v1.y, (_Float16)v1.z, (_Float16)v1.w};
    *(half8*)(Aw + (size_t)u * 8) = o;
  }

  // ---- W pack: NG*192 quad units, MFMA-fragment order ----
  const unsigned NW = NG * 192u;
  for (unsigned u = t; u < NW; u += nthr) {
    const unsigned r = u / 192u;       // W row = gate*512 + j
    const unsigned q = u - r * 192u;
    const unsigned k = q * 4u;
    float4 v;
    if (k < 256u) v = *(const float4*)(Wx + (size_t)r * I_SZ + k);
    else          v = *(const float4*)(Wh + (size_t)r * H_SZ + (k - 256u));
    const unsigned g = r >> 9, j = r & 511u;
    const unsigned nb = j >> 5, jl = j & 31u;
    const unsigned cc = jl * 4u + g;
    const unsigned wc = cc >> 6, ni = (cc >> 4) & 3u, l15 = cc & 15u;
    const unsigned kb = k >> 6, ks = (k >> 5) & 1u, l4 = (k >> 3) & 3u, e = k & 7u;
    const unsigned f = (((nb * 2u + wc) * 12u + kb) * 2u + ks) * 4u + ni;
    half4v o = {(_Float16)v.x, (_Float16)v.y, (_Float16)v.z, (_Float16)v.w};
    *(half4v*)(Wf + (size_t)f * 512 + (l4 * 16u + l15) * 8u + e) = o;
  }

  // ---- bias ----
  for (unsigned j = t; j < NG; j += nthr) bs[j] = bx[j] + bh[j];
}

// ---------------- main fused GEMM + LSTM epilogue ----------------
// Round-4 barrier-free structure (verified) + 1-deep software pipeline:
// static ping-pong register sets (afA/wfA <-> afB/wfB, compile-time indices
// only). Loads for step s+1 are issued BEFORE the MFMAs of step s -> a full
// MFMA cluster (~155cy) hides the L2 latency; compiler emits counted vmcnt.
// No LDS, no __syncthreads in the K-loop: operands are constant memory, so
// any load reordering is data-safe. Addressing via two running pointers with
// constant strides (A: 8 frags/step, W: 4 frags/step) + 1KB imm sub-offsets.
__global__ void __launch_bounds__(256) lstm_gemm(const _Float16* __restrict__ Aw,
                                                 const _Float16* __restrict__ Wf,
                                                 const float* __restrict__ bs,
                                                 const float* __restrict__ cIn,
                                                 float* __restrict__ outc,
                                                 float* __restrict__ outh) {
  __shared__ __align__(16) float Tbuf[4 * 1088];   // 4 waves x 16 rows x 68 floats

  const int t = threadIdx.x;
  const int lane = t & 63;
  const int wave = t >> 6;
  const int wr = wave >> 1, wc = wave & 1;
  const int l15 = lane & 15, l4 = lane >> 4;

  const int bid = blockIdx.x;
  const int nb = bid & 15, mb = bid >> 4;   // 16 consecutive blocks share the A panel
  const int j0 = nb * 32;
  const int m0 = mb * 128;

  // Fragment pointers. A frag index = step*8 + wr*4 + mi (step = kb*2+ks),
  // W frag index = step*4 + ni. Frag stride = 512 halves (1KB).
  const _Float16* aP = Aw + ((size_t)mb * 192 + (size_t)wr * 4) * 512 + lane * 8;
  const _Float16* wP = Wf + (size_t)(nb * 2 + wc) * 96 * 512 + lane * 8;

  // init accumulators with bias
  f32x4 acc[4][4];
#pragma unroll
  for (int ni = 0; ni < 4; ++ni) {
    int tcol = wc * 64 + ni * 16 + l15;
    int gcol = (tcol & 3) * H_SZ + j0 + (tcol >> 2);
    float b = bs[gcol];
    f32x4 v = {b, b, b, b};
#pragma unroll
    for (int mi = 0; mi < 4; ++mi) acc[mi][ni] = v;
  }

  half8 afA[4], wfA[4], afB[4], wfB[4];
  // preload step 0 into set A
#pragma unroll
  for (int i = 0; i < 4; ++i) {
    afA[i] = *(const half8*)(aP + i * 512);
    wfA[i] = *(const half8*)(wP + i * 512);
  }

  for (int s2 = 0; s2 < 11; ++s2) {
    // prefetch step 2*s2+1 into B, then MFMA step 2*s2 (set A)
    aP += 4096; wP += 2048;
#pragma unroll
    for (int i = 0; i < 4; ++i) {
      afB[i] = *(const half8*)(aP + i * 512);
      wfB[i] = *(const half8*)(wP + i * 512);
    }
#pragma unroll
    for (int mi = 0; mi < 4; ++mi)
#pragma unroll
      for (int ni = 0; ni < 4; ++ni)
        acc[mi][ni] = __builtin_amdgcn_mfma_f32_16x16x32_f16(afA[mi], wfA[ni], acc[mi][ni], 0, 0, 0);
    // prefetch step 2*s2+2 into A, then MFMA step 2*s2+1 (set B)
    aP += 4096; wP += 2048;
#pragma unroll
    for (int i = 0; i < 4; ++i) {
      afA[i] = *(const half8*)(aP + i * 512);
      wfA[i] = *(const half8*)(wP + i * 512);
    }
#pragma unroll
    for (int mi = 0; mi < 4; ++mi)
#pragma unroll
      for (int ni = 0; ni < 4; ++ni)
        acc[mi][ni] = __builtin_amdgcn_mfma_f32_16x16x32_f16(afB[mi], wfB[ni], acc[mi][ni], 0, 0, 0);
  }
  // tail: set A holds step 22; load step 23 into B, then drain both.
  aP += 4096; wP += 2048;
#pragma unroll
  for (int i = 0; i < 4; ++i) {
    afB[i] = *(const half8*)(aP + i * 512);
    wfB[i] = *(const half8*)(wP + i * 512);
  }
#pragma unroll
  for (int mi = 0; mi < 4; ++mi)
#pragma unroll
    for (int ni = 0; ni < 4; ++ni)
      acc[mi][ni] = __builtin_amdgcn_mfma_f32_16x16x32_f16(afA[mi], wfA[ni], acc[mi][ni], 0, 0, 0);
#pragma unroll
  for (int mi = 0; mi < 4; ++mi)
#pragma unroll
    for (int ni = 0; ni < 4; ++ni)
      acc[mi][ni] = __builtin_amdgcn_mfma_f32_16x16x32_f16(afB[mi], wfB[ni], acc[mi][ni], 0, 0, 0);

  // ---- epilogue: per-wave LDS transpose (stride 68 floats), wave-private ----
  float* T = Tbuf + wave * 1088;
#pragma unroll
  for (int mi = 0; mi < 4; ++mi) {
#pragma unroll
    for (int ni = 0; ni < 4; ++ni)
#pragma unroll
      for (int r = 0; r < 4; ++r)
        T[(l4 * 4 + r) * 68 + ni * 16 + l15] = acc[mi][ni][r];
#pragma unroll
    for (int orow = 0; orow < 4; ++orow) {
      int rloc = orow * 4 + l4;
      f32x4 gv = *(const f32x4*)(T + rloc * 68 + l15 * 4);
      int rowg = m0 + wr * 64 + mi * 16 + rloc;
      int jg = j0 + wc * 16 + l15;
      size_t off = (size_t)rowg * H_SZ + jg;
      float cv = cIn[off];
      float it = sigf(gv[0]);
      float ft = sigf(gv[1]);
      float ot = sigf(gv[2]);
      float tc = tanh_fast(gv[3]);
      float ct = ft * cv + it * tc;
      float ht = ot * tanh_fast(ct);
      outc[off] = ct;
      outh[off] = ht;
    }
  }
}

// ---------------- fallback (ws too small): plain fp32 ----------------
__global__ void __launch_bounds__(256) lstm_naive(const float* __restrict__ x,
                                                  const float* __restrict__ h,
                                                  const float* __restrict__ c,
                                                  const float* __restrict__ Wx,
                                                  const float* __restrict__ bx,
                                                  const float* __restrict__ Wh,
                                                  const float* __restrict__ bh,
                                                  float* __restrict__ outc,
                                                  float* __restrict__ outh) {
  int idx = blockIdx.x * 256 + threadIdx.x;
  int b = idx >> 9, j = idx & 511;
  float gi = bx[j] + bh[j];
  float gf = bx[H_SZ + j] + bh[H_SZ + j];
  float go = bx[2 * H_SZ + j] + bh[2 * H_SZ + j];
  float gc = bx[3 * H_SZ + j] + bh[3 * H_SZ + j];
  const float* xr = x + (size_t)b * I_SZ;
  for (int k = 0; k < I_SZ; ++k) {
    float xv = xr[k];
    gi += xv * Wx[(size_t)j * I_SZ + k];
    gf += xv * Wx[(size_t)(H_SZ + j) * I_SZ + k];
    go += xv * Wx[(size_t)(2 * H_SZ + j) * I_SZ + k];
    gc += xv * Wx[(size_t)(3 * H_SZ + j) * I_SZ + k];
  }
  const float* hr = h + (size_t)b * H_SZ;
  for (int k = 0; k < H_SZ; ++k) {
    float hv = hr[k];
    gi += hv * Wh[(size_t)j * H_SZ + k];
    gf += hv * Wh[(size_t)(H_SZ + j) * H_SZ + k];
    go += hv * Wh[(size_t)(2 * H_SZ + j) * H_SZ + k];
    gc += hv * Wh[(size_t)(3 * H_SZ + j) * H_SZ + k];
  }
  float it = sigf(gi), ft = sigf(gf), ot = sigf(go), tc = tanh_fast(gc);
  float ct = ft * c[idx] + it * tc;
  outc[idx] = ct;
  outh[idx] = ot * tanh_fast(ct);
}

extern "C" void kernel_launch(void* const* d_in, const int* in_sizes, int n_in,
                              void* d_out, int out_size, void* d_ws, size_t ws_size,
                              hipStream_t stream) {
  const float* x  = (const float*)d_in[0];
  const float* h  = (const float*)d_in[1];
  const float* c  = (const float*)d_in[2];
  const float* Wx = (const float*)d_in[3];
  const float* bx = (const float*)d_in[4];
  const float* Wh = (const float*)d_in[5];
  const float* bh = (const float*)d_in[6];
  float* outc = (float*)d_out;
  float* outh = outc + (size_t)B_SZ * H_SZ;

  const size_t szA = (size_t)B_SZ * K_SZ * sizeof(_Float16);
  const size_t szW = (size_t)NG * K_SZ * sizeof(_Float16);
  const size_t need = szA + szW + (size_t)NG * sizeof(float);

  if (ws_size < need) {
    lstm_naive<<<(B_SZ * H_SZ) / 256, 256, 0, stream>>>(x, h, c, Wx, bx, Wh, bh, outc, outh);
    return;
  }

  _Float16* Aw = (_Float16*)d_ws;
  _Float16* Wf = (_Float16*)((char*)d_ws + szA);
  float* bs = (float*)((char*)d_ws + szA + szW);

  prepass<<<2048, 256, 0, stream>>>(x, h, Wx, Wh, bx, bh, Aw, Wf, bs);
  lstm_gemm<<<(B_SZ / 128) * (NG / 128), 256, 0, stream>>>(Aw, Wf, bs, c, outc, outh);
}